// Round 2
// baseline (1199.432 us; speedup 1.0000x reference)
//
#include <hip/hip_runtime.h>

constexpr int Bc  = 2;
constexpr int Sc  = 2048;
constexpr int Dc  = 1024;
constexpr int Hc  = 16;
constexpr int DHc = 64;
constexpr int BS  = Bc * Sc;   // 4096 rows in flattened [B*S, D] matrices

// ---------------------------------------------------------------------------
// Generic GEMM: C[M=4096, N=1024] = A[4096,1024] @ B[1024,1024] + bias[1024]
// f32 in/out/acc. 64x64 tile, KT=32, 256 threads, 4x4 microtile.
// ---------------------------------------------------------------------------
__global__ __launch_bounds__(256, 4) void gemm_bias(
    const float* __restrict__ A, const float* __restrict__ Bm,
    const float* __restrict__ bias, float* __restrict__ C)
{
    constexpr int Kk = 1024, Nn = 1024;
    __shared__ __align__(16) float As[64][36];  // stride 36: 144B rows (16B-aligned), rows shift 4 banks
    __shared__ __align__(16) float Bs[32][64];  // reads are row-broadcast -> stride-agnostic

    const int t  = threadIdx.x;
    const int tx = t & 15, ty = t >> 4;          // tx: 4 cols, ty: 4 rows of the 64x64 tile
    const int row0 = blockIdx.y * 64;
    const int col0 = blockIdx.x * 64;

    float acc[4][4] = {};

    for (int kt = 0; kt < Kk; kt += 32) {
        __syncthreads();
        #pragma unroll
        for (int it = 0; it < 2; ++it) {
            const int s = it * 256 + t;
            // A tile: 64 rows x 32 cols = 512 float4 slots
            const int ra = s >> 3, ca = (s & 7) * 4;
            float4 va = *(const float4*)(A + (size_t)(row0 + ra) * Kk + kt + ca);
            *(float4*)&As[ra][ca] = va;
            // B tile: 32 rows x 64 cols = 512 float4 slots
            const int rb = s >> 4, cb4 = (s & 15) * 4;
            float4 vb = *(const float4*)(Bm + (size_t)(kt + rb) * Nn + col0 + cb4);
            *(float4*)&Bs[rb][cb4] = vb;
        }
        __syncthreads();
        #pragma unroll
        for (int kk = 0; kk < 32; kk += 4) {
            float4 a4[4], b4[4];
            #pragma unroll
            for (int i = 0; i < 4; ++i) a4[i] = *(const float4*)&As[ty * 4 + i][kk];
            #pragma unroll
            for (int e = 0; e < 4; ++e) b4[e] = *(const float4*)&Bs[kk + e][tx * 4];
            #pragma unroll
            for (int e = 0; e < 4; ++e) {
                #pragma unroll
                for (int i = 0; i < 4; ++i) {
                    const float av = (&a4[i].x)[e];
                    acc[i][0] += av * b4[e].x;
                    acc[i][1] += av * b4[e].y;
                    acc[i][2] += av * b4[e].z;
                    acc[i][3] += av * b4[e].w;
                }
            }
        }
    }

    const int cb = col0 + tx * 4;
    const float4 bv = *(const float4*)(bias + cb);
    #pragma unroll
    for (int i = 0; i < 4; ++i) {
        float4 o;
        o.x = acc[i][0] + bv.x;
        o.y = acc[i][1] + bv.y;
        o.z = acc[i][2] + bv.z;
        o.w = acc[i][3] + bv.w;
        *(float4*)(C + (size_t)(row0 + ty * 4 + i) * Nn + cb) = o;
    }
}

// ---------------------------------------------------------------------------
// Flash-style attention over the STRICT-UPPER mask (attend j > i).
// Block: 256 thr, 64 q-rows of one (b,h). Streams 32-key tiles.
// Q,K,V,CTX are [4096, 1024] f32 matrices (col = h*64 + dh).
// LDS: 17.4 + 9.2 + 8.7 + 9.2 = 44.5 KB.
// ---------------------------------------------------------------------------
__global__ __launch_bounds__(256, 2) void attn_kernel(
    const float* __restrict__ Qg, const float* __restrict__ Kg,
    const float* __restrict__ Vg, float* __restrict__ CTX)
{
    __shared__ __align__(16) float Qs [64][68];  // [q_row][d]
    __shared__ __align__(16) float KsT[64][36];  // [d][key]   (transposed)
    __shared__ __align__(16) float Vs [32][68];  // [key][d]
    __shared__ __align__(16) float Ps [64][36];  // [q_row][key]

    const int t  = threadIdx.x;
    const int tx = t & 15, ty = t >> 4;
    const int q0 = blockIdx.x * 64;
    const int h  = blockIdx.y;
    const int b  = blockIdx.z;
    const size_t rb = (size_t)b * Sc;
    const int cb = h * DHc;

    // stage Q tile: 64 rows x 64 dims = 1024 float4 slots, 4 per thread
    #pragma unroll
    for (int it = 0; it < 4; ++it) {
        const int s = it * 256 + t;
        const int r = s >> 4, c4 = (s & 15) * 4;
        float4 v = *(const float4*)(Qg + (rb + q0 + r) * (size_t)Dc + cb + c4);
        *(float4*)&Qs[r][c4] = v;
    }

    float m[4], l[4], O[4][4];
    #pragma unroll
    for (int i = 0; i < 4; ++i) {
        m[i] = -3.0e38f; l[i] = 0.f;
        #pragma unroll
        for (int j = 0; j < 4; ++j) O[i][j] = 0.f;
    }
    const float scale = 0.125f;  // 1/sqrt(64)

    // Tiles with k0+31 <= q0 are fully masked for every row in the block ->
    // exact zero contribution after rescale, skip them. EXCEPT the last
    // q-block: row S-1 has zero allowed keys; the reference softmaxes
    // (score - 1e9) over ALL keys there, so it must see every tile.
    const int k0_start = (q0 == Sc - 64) ? 0 : q0;

    for (int k0 = k0_start; k0 < Sc; k0 += 32) {
        __syncthreads();
        // stage K (transposed) and V: 32 keys x 64 dims = 512 float4 slots
        #pragma unroll
        for (int it = 0; it < 2; ++it) {
            const int s = it * 256 + t;
            const int r = s >> 4;          // key 0..31
            const int c4 = (s & 15) * 4;   // d
            const size_t g = (rb + k0 + r) * (size_t)Dc + cb + c4;
            float4 vk = *(const float4*)(Kg + g);
            KsT[c4 + 0][r] = vk.x;
            KsT[c4 + 1][r] = vk.y;
            KsT[c4 + 2][r] = vk.z;
            KsT[c4 + 3][r] = vk.w;
            float4 vv = *(const float4*)(Vg + g);
            *(float4*)&Vs[r][c4] = vv;
        }
        __syncthreads();

        // scores: sc[i][j] = Q[q0+ty*4+i] . K[k0+tx*2+j], j in {0,1}
        float sc[4][2] = {};
        #pragma unroll
        for (int d = 0; d < 64; d += 4) {
            float4 q4[4]; float2 k2[4];
            #pragma unroll
            for (int i = 0; i < 4; ++i) q4[i] = *(const float4*)&Qs[ty * 4 + i][d];
            #pragma unroll
            for (int e = 0; e < 4; ++e) k2[e] = *(const float2*)&KsT[d + e][tx * 2];
            #pragma unroll
            for (int e = 0; e < 4; ++e) {
                #pragma unroll
                for (int i = 0; i < 4; ++i) {
                    const float qv = (&q4[i].x)[e];
                    sc[i][0] += qv * k2[e].x;
                    sc[i][1] += qv * k2[e].y;
                }
            }
        }

        // mask + scale, per-row tile max
        float pmax[4];
        #pragma unroll
        for (int i = 0; i < 4; ++i) {
            const int qi = q0 + ty * 4 + i;
            float mx = -3.0e38f;
            #pragma unroll
            for (int j = 0; j < 2; ++j) {
                const int kj = k0 + tx * 2 + j;
                float s = sc[i][j] * scale + ((kj > qi) ? 0.f : -1e9f);
                sc[i][j] = s;
                mx = fmaxf(mx, s);
            }
            pmax[i] = mx;
        }
        #pragma unroll
        for (int off = 1; off < 16; off <<= 1) {
            #pragma unroll
            for (int i = 0; i < 4; ++i)
                pmax[i] = fmaxf(pmax[i], __shfl_xor(pmax[i], off, 64));
        }

        // online softmax update (state replicated across the 16 tx lanes)
        float alpha[4], lsum[4];
        #pragma unroll
        for (int i = 0; i < 4; ++i) {
            const float mn = fmaxf(m[i], pmax[i]);
            alpha[i] = __expf(m[i] - mn);
            m[i] = mn;
            float s0 = 0.f;
            #pragma unroll
            for (int j = 0; j < 2; ++j) {
                const float p = __expf(sc[i][j] - mn);
                sc[i][j] = p;
                s0 += p;
            }
            lsum[i] = s0;
        }
        #pragma unroll
        for (int off = 1; off < 16; off <<= 1) {
            #pragma unroll
            for (int i = 0; i < 4; ++i)
                lsum[i] += __shfl_xor(lsum[i], off, 64);
        }
        #pragma unroll
        for (int i = 0; i < 4; ++i) l[i] = l[i] * alpha[i] + lsum[i];

        // publish P tile
        #pragma unroll
        for (int i = 0; i < 4; ++i)
            #pragma unroll
            for (int j = 0; j < 2; ++j)
                Ps[ty * 4 + i][tx * 2 + j] = sc[i][j];
        __syncthreads();

        // O = O*alpha + P @ V   (O[i][j]: row ty*4+i, dh tx*4+j)
        #pragma unroll
        for (int i = 0; i < 4; ++i)
            #pragma unroll
            for (int j = 0; j < 4; ++j)
                O[i][j] *= alpha[i];
        #pragma unroll
        for (int kk = 0; kk < 32; kk += 4) {
            float4 p4[4], v4[4];
            #pragma unroll
            for (int i = 0; i < 4; ++i) p4[i] = *(const float4*)&Ps[ty * 4 + i][kk];
            #pragma unroll
            for (int e = 0; e < 4; ++e) v4[e] = *(const float4*)&Vs[kk + e][tx * 4];
            #pragma unroll
            for (int e = 0; e < 4; ++e) {
                #pragma unroll
                for (int i = 0; i < 4; ++i) {
                    const float pv = (&p4[i].x)[e];
                    O[i][0] += pv * v4[e].x;
                    O[i][1] += pv * v4[e].y;
                    O[i][2] += pv * v4[e].z;
                    O[i][3] += pv * v4[e].w;
                }
            }
        }
    }

    #pragma unroll
    for (int i = 0; i < 4; ++i) {
        const float rl = 1.0f / l[i];
        float4 o;
        o.x = O[i][0] * rl; o.y = O[i][1] * rl;
        o.z = O[i][2] * rl; o.w = O[i][3] * rl;
        *(float4*)(CTX + (rb + q0 + ty * 4 + i) * (size_t)Dc + cb + tx * 4) = o;
    }
}

// ---------------------------------------------------------------------------
// out = LayerNorm(x + attn_out) * gamma + beta, one block per row
// ---------------------------------------------------------------------------
__global__ __launch_bounds__(256, 4) void resid_ln(
    const float* __restrict__ X, const float* __restrict__ AO,
    const float* __restrict__ gamma, const float* __restrict__ beta,
    float* __restrict__ out)
{
    const int r = blockIdx.x;
    const int t = threadIdx.x;
    const size_t base = (size_t)r * Dc + t * 4;

    const float4 x4 = *(const float4*)(X + base);
    const float4 a4 = *(const float4*)(AO + base);
    float y[4];
    y[0] = x4.x + a4.x;
    y[1] = x4.y + a4.y;
    y[2] = x4.z + a4.z;
    y[3] = x4.w + a4.w;

    float s  = y[0] + y[1] + y[2] + y[3];
    float s2 = y[0]*y[0] + y[1]*y[1] + y[2]*y[2] + y[3]*y[3];
    #pragma unroll
    for (int off = 1; off < 64; off <<= 1) {
        s  += __shfl_xor(s,  off, 64);
        s2 += __shfl_xor(s2, off, 64);
    }
    __shared__ float red[8];
    const int w = t >> 6;
    if ((t & 63) == 0) { red[w] = s; red[4 + w] = s2; }
    __syncthreads();
    s  = red[0] + red[1] + red[2] + red[3];
    s2 = red[4] + red[5] + red[6] + red[7];

    const float mu   = s * (1.0f / Dc);
    const float rstd = rsqrtf(s2 * (1.0f / Dc) - mu * mu + 1e-6f);

    const float4 g4 = *(const float4*)(gamma + t * 4);
    const float4 b4 = *(const float4*)(beta  + t * 4);
    float4 o;
    o.x = (y[0] - mu) * rstd * g4.x + b4.x;
    o.y = (y[1] - mu) * rstd * g4.y + b4.y;
    o.z = (y[2] - mu) * rstd * g4.z + b4.z;
    o.w = (y[3] - mu) * rstd * g4.w + b4.w;
    *(float4*)(out + base) = o;
}

// ---------------------------------------------------------------------------
extern "C" void kernel_launch(void* const* d_in, const int* in_sizes, int n_in,
                              void* d_out, int out_size, void* d_ws, size_t ws_size,
                              hipStream_t stream)
{
    (void)in_sizes; (void)n_in; (void)out_size; (void)ws_size;
    const float* x     = (const float*)d_in[0];
    const float* Wq    = (const float*)d_in[1];
    const float* bq    = (const float*)d_in[2];
    const float* Wk    = (const float*)d_in[3];
    const float* bk    = (const float*)d_in[4];
    const float* Wv    = (const float*)d_in[5];
    const float* bv    = (const float*)d_in[6];
    const float* Wo    = (const float*)d_in[7];
    const float* bo    = (const float*)d_in[8];
    const float* gamma = (const float*)d_in[9];
    const float* beta  = (const float*)d_in[10];
    float* out = (float*)d_out;

    const size_t matN = (size_t)BS * Dc;  // 4096*1024 elements = 16 MB f32
    float* Qb = (float*)d_ws;
    float* Kb = Qb + matN;
    float* Vb = Kb + matN;
    float* Cx = Vb + matN;
    float* AO = Qb;  // Q buffer is dead after attention -> reuse for out-proj

    dim3 gg(Dc / 64, BS / 64);  // (16, 64)
    gemm_bias<<<gg, 256, 0, stream>>>(x, Wq, bq, Qb);
    gemm_bias<<<gg, 256, 0, stream>>>(x, Wk, bk, Kb);
    gemm_bias<<<gg, 256, 0, stream>>>(x, Wv, bv, Vb);

    dim3 ga(Sc / 64, Hc, Bc);   // (32, 16, 2)
    attn_kernel<<<ga, 256, 0, stream>>>(Qb, Kb, Vb, Cx);

    gemm_bias<<<gg, 256, 0, stream>>>(Cx, Wo, bo, AO);

    resid_ln<<<BS, 256, 0, stream>>>(x, AO, gamma, beta, out);
}

// Round 3
// 355.742 us; speedup vs baseline: 3.3716x; 3.3716x over previous
//
#include <hip/hip_runtime.h>
#include <hip/hip_bf16.h>

typedef __hip_bfloat16 bf16;
typedef __attribute__((ext_vector_type(8))) short bf16x8;   // 8 bf16 = 4 VGPRs
typedef __attribute__((ext_vector_type(4))) float f32x4;

constexpr int Bc  = 2;
constexpr int Sc  = 2048;
constexpr int Dc  = 1024;
constexpr int Hc  = 16;
constexpr int DHc = 64;
constexpr int BS  = Bc * Sc;   // 4096 rows

__device__ __forceinline__ float bs2f(unsigned short u) {
    union { unsigned int i; float f; } v; v.i = ((unsigned int)u) << 16; return v.f;
}
__device__ __forceinline__ short f2bs(float x) {
    bf16 h = __float2bfloat16(x);
    return *reinterpret_cast<short*>(&h);
}

// ---------------------------------------------------------------------------
// cast x (f32) -> bf16, same layout
// ---------------------------------------------------------------------------
__global__ __launch_bounds__(256) void cast_x(const float* __restrict__ in,
                                              short* __restrict__ out) {
    const int i = (blockIdx.x * 256 + threadIdx.x) * 4;
    const float4 v = *(const float4*)(in + i);
    ushort4 o;
    o.x = (unsigned short)f2bs(v.x);
    o.y = (unsigned short)f2bs(v.y);
    o.z = (unsigned short)f2bs(v.z);
    o.w = (unsigned short)f2bs(v.w);
    *(ushort4*)(out + i) = o;
}

// ---------------------------------------------------------------------------
// transpose + cast: in f32 [1024 k][1024 n] -> out bf16 [n][k].  z picks W.
// ---------------------------------------------------------------------------
__global__ __launch_bounds__(256) void transpose_cast(
    const float* __restrict__ w0, const float* __restrict__ w1,
    const float* __restrict__ w2, const float* __restrict__ w3,
    short* __restrict__ outbase)
{
    __shared__ float T[64][65];
    const int z = blockIdx.z;
    const float* in = (z == 0) ? w0 : (z == 1) ? w1 : (z == 2) ? w2 : w3;
    short* out = outbase + (size_t)z * 1024 * 1024;
    const int k0 = blockIdx.x * 64, n0 = blockIdx.y * 64;
    const int t = threadIdx.x;
    #pragma unroll
    for (int it = 0; it < 4; ++it) {
        const int s = it * 256 + t;
        const int r = s >> 4, c = (s & 15) * 4;
        *(float4*)&T[r][c] = *(const float4*)(in + (size_t)(k0 + r) * 1024 + n0 + c);
    }
    __syncthreads();
    #pragma unroll
    for (int it = 0; it < 4; ++it) {
        const int s = it * 256 + t;
        const int rr = s >> 4, cc = (s & 15) * 4;   // rr: n-local, cc: k-local
        ushort4 o;
        o.x = (unsigned short)f2bs(T[cc + 0][rr]);
        o.y = (unsigned short)f2bs(T[cc + 1][rr]);
        o.z = (unsigned short)f2bs(T[cc + 2][rr]);
        o.w = (unsigned short)f2bs(T[cc + 3][rr]);
        *(ushort4*)(out + (size_t)(n0 + rr) * 1024 + k0 + cc) = o;
    }
}

// ---------------------------------------------------------------------------
// MFMA GEMM: C[z][4096][1024] = A[4096][1024] @ BT[z][n][k]^T + bias[z]
// bf16 in/out, f32 acc. 128x128 tile, BK=64, 256 thr = 4 waves of 64x64.
// ---------------------------------------------------------------------------
__global__ __launch_bounds__(256, 2) void gemm_bt(
    const short* __restrict__ A, const short* __restrict__ BTbase,
    const float* __restrict__ b0, const float* __restrict__ b1,
    const float* __restrict__ b2, short* __restrict__ Cbase)
{
    __shared__ __align__(16) short As[128][72];
    __shared__ __align__(16) short Bs[128][72];

    const int z = blockIdx.z;
    const short* BT = BTbase + (size_t)z * 1024 * 1024;
    const float* bias = (z == 0) ? b0 : (z == 1) ? b1 : b2;
    short* C = Cbase + (size_t)z * BS * Dc;

    const int t = threadIdx.x;
    const int lane = t & 63, w = t >> 6;
    const int quad = lane >> 4, l16 = lane & 15;
    const int wm = (w & 1) * 64, wn = (w >> 1) * 64;
    const int row0 = blockIdx.y * 128;
    const int col0 = blockIdx.x * 128;

    const int sr = t >> 1, sg = t & 1;   // staging: row, 32-elem segment

    f32x4 acc[4][4] = {};

    for (int kt = 0; kt < 1024; kt += 64) {
        __syncthreads();
        {
            const short* ap = A  + (size_t)(row0 + sr) * 1024 + kt + sg * 32;
            const short* bp = BT + (size_t)(col0 + sr) * 1024 + kt + sg * 32;
            #pragma unroll
            for (int i = 0; i < 4; ++i) {
                *(bf16x8*)&As[sr][sg * 32 + i * 8] = *(const bf16x8*)(ap + i * 8);
                *(bf16x8*)&Bs[sr][sg * 32 + i * 8] = *(const bf16x8*)(bp + i * 8);
            }
        }
        __syncthreads();
        #pragma unroll
        for (int ks = 0; ks < 2; ++ks) {
            bf16x8 av[4], bv[4];
            #pragma unroll
            for (int mt = 0; mt < 4; ++mt)
                av[mt] = *(const bf16x8*)&As[wm + mt * 16 + l16][ks * 32 + quad * 8];
            #pragma unroll
            for (int nt = 0; nt < 4; ++nt)
                bv[nt] = *(const bf16x8*)&Bs[wn + nt * 16 + l16][ks * 32 + quad * 8];
            #pragma unroll
            for (int mt = 0; mt < 4; ++mt)
                #pragma unroll
                for (int nt = 0; nt < 4; ++nt)
                    acc[mt][nt] = __builtin_amdgcn_mfma_f32_16x16x32_bf16(
                        av[mt], bv[nt], acc[mt][nt], 0, 0, 0);
        }
    }

    float bvv[4];
    #pragma unroll
    for (int nt = 0; nt < 4; ++nt) bvv[nt] = bias[col0 + wn + nt * 16 + l16];
    #pragma unroll
    for (int mt = 0; mt < 4; ++mt)
        #pragma unroll
        for (int reg = 0; reg < 4; ++reg) {
            const size_t row = row0 + wm + mt * 16 + quad * 4 + reg;
            #pragma unroll
            for (int nt = 0; nt < 4; ++nt) {
                const int col = col0 + wn + nt * 16 + l16;
                C[row * 1024 + col] = f2bs(acc[mt][nt][reg] + bvv[nt]);
            }
        }
}

// ---------------------------------------------------------------------------
// MFMA flash attention, strict-upper mask (attend j > i).
// Block: 256 thr = 4 waves; wave w owns q rows [q0+w*16, +16). 64-key tiles.
// Q,K frags straight from global (contiguous in d). V staged transposed.
// P round-trips per-wave LDS (C-layout -> A-layout).
// ---------------------------------------------------------------------------
__global__ __launch_bounds__(256, 2) void attn_mfma(
    const short* __restrict__ Qg, const short* __restrict__ Kg,
    const short* __restrict__ Vg, short* __restrict__ CTX)
{
    __shared__ __align__(16) short VsT[64][72];      // [dh][key]
    __shared__ __align__(16) short Ps[4][16][72];    // per-wave [m][key]

    const int t = threadIdx.x;
    const int lane = t & 63, w = t >> 6;
    const int quad = lane >> 4, l16 = lane & 15;
    const int q0 = blockIdx.x * 64;
    const int h  = blockIdx.y;
    const int b  = blockIdx.z;
    const size_t rb = (size_t)b * Sc;
    const int cb = h * DHc;

    // Q fragments: A-operand, m = l16 within wave's 16 rows, k = quad*8+j
    bf16x8 qf[2];
    {
        const short* qp = Qg + (rb + q0 + w * 16 + l16) * (size_t)Dc + cb + quad * 8;
        qf[0] = *(const bf16x8*)(qp);
        qf[1] = *(const bf16x8*)(qp + 32);
    }

    float m[4], l[4];
    f32x4 O[4] = {};   // O[nt][reg]: row quad*4+reg, dh nt*16+l16
    #pragma unroll
    for (int i = 0; i < 4; ++i) { m[i] = -3.0e38f; l[i] = 0.f; }

    const int vkey = t & 63, vdh0 = (t >> 6) * 16;   // V staging assignment
    const int k0_start = (q0 == Sc - 64) ? 0 : q0;

    for (int k0 = k0_start; k0 < Sc; k0 += 64) {
        // K fragments for this tile (global, no LDS): B[k=d][n=key]
        bf16x8 kf[2][4];
        #pragma unroll
        for (int nt = 0; nt < 4; ++nt) {
            const short* kp = Kg + (rb + k0 + nt * 16 + l16) * (size_t)Dc + cb + quad * 8;
            kf[0][nt] = *(const bf16x8*)(kp);
            kf[1][nt] = *(const bf16x8*)(kp + 32);
        }
        // V tile prefetch (global)
        const short* vp = Vg + (rb + k0 + vkey) * (size_t)Dc + cb + vdh0;
        bf16x8 v0 = *(const bf16x8*)(vp);
        bf16x8 v1 = *(const bf16x8*)(vp + 8);

        __syncthreads();   // previous PV reads of VsT done
        #pragma unroll
        for (int e = 0; e < 8; ++e) {
            VsT[vdh0 + e][vkey]     = v0[e];
            VsT[vdh0 + 8 + e][vkey] = v1[e];
        }
        __syncthreads();

        // scores S = Q . K^T  (f32 acc)
        f32x4 S[4] = {};
        #pragma unroll
        for (int ks = 0; ks < 2; ++ks)
            #pragma unroll
            for (int nt = 0; nt < 4; ++nt)
                S[nt] = __builtin_amdgcn_mfma_f32_16x16x32_bf16(qf[ks], kf[ks][nt], S[nt], 0, 0, 0);

        // mask + scale; exact -1e9f on masked entries (matches f32 reference rounding)
        float mrow[4];
        #pragma unroll
        for (int reg = 0; reg < 4; ++reg) mrow[reg] = -3.0e38f;
        #pragma unroll
        for (int nt = 0; nt < 4; ++nt) {
            const int col = k0 + nt * 16 + l16;
            #pragma unroll
            for (int reg = 0; reg < 4; ++reg) {
                const int row = q0 + w * 16 + quad * 4 + reg;
                const float s = (col > row) ? S[nt][reg] * 0.125f : -1e9f;
                S[nt][reg] = s;
                mrow[reg] = fmaxf(mrow[reg], s);
            }
        }
        #pragma unroll
        for (int off = 1; off < 16; off <<= 1)
            #pragma unroll
            for (int reg = 0; reg < 4; ++reg)
                mrow[reg] = fmaxf(mrow[reg], __shfl_xor(mrow[reg], off, 64));

        float alpha[4], ls[4];
        #pragma unroll
        for (int reg = 0; reg < 4; ++reg) {
            const float mn = fmaxf(m[reg], mrow[reg]);
            alpha[reg] = __expf(m[reg] - mn);
            m[reg] = mn;
            ls[reg] = 0.f;
        }
        #pragma unroll
        for (int nt = 0; nt < 4; ++nt)
            #pragma unroll
            for (int reg = 0; reg < 4; ++reg) {
                const float p = __expf(S[nt][reg] - m[reg]);
                S[nt][reg] = p;
                ls[reg] += p;
            }
        #pragma unroll
        for (int off = 1; off < 16; off <<= 1)
            #pragma unroll
            for (int reg = 0; reg < 4; ++reg)
                ls[reg] += __shfl_xor(ls[reg], off, 64);
        #pragma unroll
        for (int reg = 0; reg < 4; ++reg) l[reg] = l[reg] * alpha[reg] + ls[reg];

        // O rescale + publish P (C-layout -> LDS, wave-local)
        #pragma unroll
        for (int nt = 0; nt < 4; ++nt)
            #pragma unroll
            for (int reg = 0; reg < 4; ++reg) {
                O[nt][reg] *= alpha[reg];
                Ps[w][quad * 4 + reg][nt * 16 + l16] = f2bs(S[nt][reg]);
            }

        // PV: A = P[16 x 64keys] (from Ps), B = V[key][dh] (from VsT)
        #pragma unroll
        for (int ks = 0; ks < 2; ++ks) {
            const bf16x8 pf = *(const bf16x8*)&Ps[w][l16][ks * 32 + quad * 8];
            #pragma unroll
            for (int nt = 0; nt < 4; ++nt) {
                const bf16x8 vf = *(const bf16x8*)&VsT[nt * 16 + l16][ks * 32 + quad * 8];
                O[nt] = __builtin_amdgcn_mfma_f32_16x16x32_bf16(pf, vf, O[nt], 0, 0, 0);
            }
        }
    }

    float rl[4];
    #pragma unroll
    for (int reg = 0; reg < 4; ++reg) rl[reg] = 1.0f / l[reg];
    #pragma unroll
    for (int nt = 0; nt < 4; ++nt)
        #pragma unroll
        for (int reg = 0; reg < 4; ++reg) {
            const size_t row = rb + q0 + w * 16 + quad * 4 + reg;
            CTX[row * Dc + cb + nt * 16 + l16] = f2bs(O[nt][reg] * rl[reg]);
        }
}

// ---------------------------------------------------------------------------
// out = LayerNorm(x + attn_out) * gamma + beta; x f32, AO bf16, out f32
// ---------------------------------------------------------------------------
__global__ __launch_bounds__(256, 4) void resid_ln(
    const float* __restrict__ X, const short* __restrict__ AO,
    const float* __restrict__ gamma, const float* __restrict__ beta,
    float* __restrict__ out)
{
    const int r = blockIdx.x;
    const int t = threadIdx.x;
    const size_t base = (size_t)r * Dc + t * 4;

    const float4 x4 = *(const float4*)(X + base);
    const ushort4 a4 = *(const ushort4*)(AO + base);
    float y[4];
    y[0] = x4.x + bs2f(a4.x);
    y[1] = x4.y + bs2f(a4.y);
    y[2] = x4.z + bs2f(a4.z);
    y[3] = x4.w + bs2f(a4.w);

    float s  = y[0] + y[1] + y[2] + y[3];
    float s2 = y[0]*y[0] + y[1]*y[1] + y[2]*y[2] + y[3]*y[3];
    #pragma unroll
    for (int off = 1; off < 64; off <<= 1) {
        s  += __shfl_xor(s,  off, 64);
        s2 += __shfl_xor(s2, off, 64);
    }
    __shared__ float red[8];
    const int w = t >> 6;
    if ((t & 63) == 0) { red[w] = s; red[4 + w] = s2; }
    __syncthreads();
    s  = red[0] + red[1] + red[2] + red[3];
    s2 = red[4] + red[5] + red[6] + red[7];

    const float mu   = s * (1.0f / Dc);
    const float rstd = rsqrtf(s2 * (1.0f / Dc) - mu * mu + 1e-6f);

    const float4 g4 = *(const float4*)(gamma + t * 4);
    const float4 b4 = *(const float4*)(beta  + t * 4);
    float4 o;
    o.x = (y[0] - mu) * rstd * g4.x + b4.x;
    o.y = (y[1] - mu) * rstd * g4.y + b4.y;
    o.z = (y[2] - mu) * rstd * g4.z + b4.z;
    o.w = (y[3] - mu) * rstd * g4.w + b4.w;
    *(float4*)(out + base) = o;
}

// ---------------------------------------------------------------------------
extern "C" void kernel_launch(void* const* d_in, const int* in_sizes, int n_in,
                              void* d_out, int out_size, void* d_ws, size_t ws_size,
                              hipStream_t stream)
{
    (void)in_sizes; (void)n_in; (void)out_size; (void)ws_size;
    const float* x     = (const float*)d_in[0];
    const float* Wq    = (const float*)d_in[1];
    const float* bq    = (const float*)d_in[2];
    const float* Wk    = (const float*)d_in[3];
    const float* bk    = (const float*)d_in[4];
    const float* Wv    = (const float*)d_in[5];
    const float* bv    = (const float*)d_in[6];
    const float* Wo    = (const float*)d_in[7];
    const float* bo    = (const float*)d_in[8];
    const float* gamma = (const float*)d_in[9];
    const float* beta  = (const float*)d_in[10];
    float* out = (float*)d_out;

    const size_t matN = (size_t)BS * Dc;       // 4,194,304
    const size_t wN   = (size_t)Dc * Dc;       // 1,048,576
    short* xb = (short*)d_ws;
    short* WT = xb + matN;                     // 4 transposed weights
    short* Qb = WT + 4 * wN;
    short* Kb = Qb + matN;
    short* Vb = Kb + matN;
    short* Cx = Vb + matN;
    short* AO = Qb;                            // reuse after attention

    cast_x<<<matN / 1024, 256, 0, stream>>>(x, xb);

    dim3 gt(16, 16, 4);
    transpose_cast<<<gt, 256, 0, stream>>>(Wq, Wk, Wv, Wo, WT);

    dim3 gq(Dc / 128, BS / 128, 3);            // (8, 32, 3)
    gemm_bt<<<gq, 256, 0, stream>>>(xb, WT, bq, bk, bv, Qb);

    dim3 ga(Sc / 64, Hc, Bc);                  // (32, 16, 2)
    attn_mfma<<<ga, 256, 0, stream>>>(Qb, Kb, Vb, Cx);

    dim3 go(Dc / 128, BS / 128, 1);
    gemm_bt<<<go, 256, 0, stream>>>(Cx, WT + 3 * wN, bo, bo, bo, AO);

    resid_ln<<<BS, 256, 0, stream>>>(x, AO, gamma, beta, out);
}

// Round 4
// 310.690 us; speedup vs baseline: 3.8605x; 1.1450x over previous
//
#include <hip/hip_runtime.h>
#include <hip/hip_bf16.h>

typedef __hip_bfloat16 bf16;
typedef __attribute__((ext_vector_type(8))) short bf16x8;   // 8 bf16 = 4 VGPRs
typedef __attribute__((ext_vector_type(4))) float f32x4;

constexpr int Bc  = 2;
constexpr int Sc  = 2048;
constexpr int Dc  = 1024;
constexpr int Hc  = 16;
constexpr int DHc = 64;
constexpr int BS  = Bc * Sc;   // 4096 rows
constexpr int NT  = Sc / 64;   // 32 key tiles

__device__ __forceinline__ float bs2f(unsigned short u) {
    union { unsigned int i; float f; } v; v.i = ((unsigned int)u) << 16; return v.f;
}
__device__ __forceinline__ short f2bs(float x) {
    bf16 h = __float2bfloat16(x);
    return *reinterpret_cast<short*>(&h);
}

// ---------------------------------------------------------------------------
// cast x (f32) -> bf16, same layout
// ---------------------------------------------------------------------------
__global__ __launch_bounds__(256) void cast_x(const float* __restrict__ in,
                                              short* __restrict__ out) {
    const int i = (blockIdx.x * 256 + threadIdx.x) * 4;
    const float4 v = *(const float4*)(in + i);
    ushort4 o;
    o.x = (unsigned short)f2bs(v.x);
    o.y = (unsigned short)f2bs(v.y);
    o.z = (unsigned short)f2bs(v.z);
    o.w = (unsigned short)f2bs(v.w);
    *(ushort4*)(out + i) = o;
}

// ---------------------------------------------------------------------------
// transpose + cast: in f32 [1024 k][1024 n] -> out bf16 [n][k].  z picks W.
// ---------------------------------------------------------------------------
__global__ __launch_bounds__(256) void transpose_cast(
    const float* __restrict__ w0, const float* __restrict__ w1,
    const float* __restrict__ w2, const float* __restrict__ w3,
    short* __restrict__ outbase)
{
    __shared__ float T[64][65];
    const int z = blockIdx.z;
    const float* in = (z == 0) ? w0 : (z == 1) ? w1 : (z == 2) ? w2 : w3;
    short* out = outbase + (size_t)z * 1024 * 1024;
    const int k0 = blockIdx.x * 64, n0 = blockIdx.y * 64;
    const int t = threadIdx.x;
    #pragma unroll
    for (int it = 0; it < 4; ++it) {
        const int s = it * 256 + t;
        const int r = s >> 4, c = (s & 15) * 4;
        *(float4*)&T[r][c] = *(const float4*)(in + (size_t)(k0 + r) * 1024 + n0 + c);
    }
    __syncthreads();
    #pragma unroll
    for (int it = 0; it < 4; ++it) {
        const int s = it * 256 + t;
        const int rr = s >> 4, cc = (s & 15) * 4;   // rr: n-local, cc: k-local
        ushort4 o;
        o.x = (unsigned short)f2bs(T[cc + 0][rr]);
        o.y = (unsigned short)f2bs(T[cc + 1][rr]);
        o.z = (unsigned short)f2bs(T[cc + 2][rr]);
        o.w = (unsigned short)f2bs(T[cc + 3][rr]);
        *(ushort4*)(out + (size_t)(n0 + rr) * 1024 + k0 + cc) = o;
    }
}

// ---------------------------------------------------------------------------
// MFMA GEMM: C[z][4096][1024] = A[4096][1024] @ BT[z][n][k]^T + bias[z]
// bf16 in/out, f32 acc. 128x128 tile, BK=64, 256 thr = 4 waves of 64x64.
// ---------------------------------------------------------------------------
__global__ __launch_bounds__(256, 2) void gemm_bt(
    const short* __restrict__ A, const short* __restrict__ BTbase,
    const float* __restrict__ b0, const float* __restrict__ b1,
    const float* __restrict__ b2, short* __restrict__ Cbase)
{
    __shared__ __align__(16) short As[128][72];
    __shared__ __align__(16) short Bs[128][72];

    const int z = blockIdx.z;
    const short* BT = BTbase + (size_t)z * 1024 * 1024;
    const float* bias = (z == 0) ? b0 : (z == 1) ? b1 : b2;
    short* C = Cbase + (size_t)z * BS * Dc;

    const int t = threadIdx.x;
    const int lane = t & 63, w = t >> 6;
    const int quad = lane >> 4, l16 = lane & 15;
    const int wm = (w & 1) * 64, wn = (w >> 1) * 64;
    const int row0 = blockIdx.y * 128;
    const int col0 = blockIdx.x * 128;

    const int sr = t >> 1, sg = t & 1;   // staging: row, 32-elem segment

    f32x4 acc[4][4] = {};

    for (int kt = 0; kt < 1024; kt += 64) {
        __syncthreads();
        {
            const short* ap = A  + (size_t)(row0 + sr) * 1024 + kt + sg * 32;
            const short* bp = BT + (size_t)(col0 + sr) * 1024 + kt + sg * 32;
            #pragma unroll
            for (int i = 0; i < 4; ++i) {
                *(bf16x8*)&As[sr][sg * 32 + i * 8] = *(const bf16x8*)(ap + i * 8);
                *(bf16x8*)&Bs[sr][sg * 32 + i * 8] = *(const bf16x8*)(bp + i * 8);
            }
        }
        __syncthreads();
        #pragma unroll
        for (int ks = 0; ks < 2; ++ks) {
            bf16x8 av[4], bv[4];
            #pragma unroll
            for (int mt = 0; mt < 4; ++mt)
                av[mt] = *(const bf16x8*)&As[wm + mt * 16 + l16][ks * 32 + quad * 8];
            #pragma unroll
            for (int nt = 0; nt < 4; ++nt)
                bv[nt] = *(const bf16x8*)&Bs[wn + nt * 16 + l16][ks * 32 + quad * 8];
            #pragma unroll
            for (int mt = 0; mt < 4; ++mt)
                #pragma unroll
                for (int nt = 0; nt < 4; ++nt)
                    acc[mt][nt] = __builtin_amdgcn_mfma_f32_16x16x32_bf16(
                        av[mt], bv[nt], acc[mt][nt], 0, 0, 0);
        }
    }

    float bvv[4];
    #pragma unroll
    for (int nt = 0; nt < 4; ++nt) bvv[nt] = bias[col0 + wn + nt * 16 + l16];
    #pragma unroll
    for (int mt = 0; mt < 4; ++mt)
        #pragma unroll
        for (int reg = 0; reg < 4; ++reg) {
            const size_t row = row0 + wm + mt * 16 + quad * 4 + reg;
            #pragma unroll
            for (int nt = 0; nt < 4; ++nt) {
                const int col = col0 + wn + nt * 16 + l16;
                C[row * 1024 + col] = f2bs(acc[mt][nt][reg] + bvv[nt]);
            }
        }
}

// ---------------------------------------------------------------------------
// softmax + PV for one 16-row q-fragment against the staged 64-key tile.
// Layouts (HW-validated in R3): A-frag A[m=l16][k=quad*8+j]; B-frag
// B[k=quad*8+j][n=l16]; C/D row=quad*4+reg, col=l16.
// ---------------------------------------------------------------------------
__device__ __forceinline__ void qtile_step(
    const bf16x8 (&qf)[2], const bf16x8 (&kf)[2][4],
    const short (&VsT)[64][72], short (&Psw)[16][72],
    const int k0, const int row_base,           // row = row_base + quad*4 + reg
    const int quad, const int l16,
    float (&m)[4], float (&l)[4], f32x4 (&O)[4])
{
    f32x4 S[4] = {};
    #pragma unroll
    for (int ks = 0; ks < 2; ++ks)
        #pragma unroll
        for (int nt = 0; nt < 4; ++nt)
            S[nt] = __builtin_amdgcn_mfma_f32_16x16x32_bf16(qf[ks], kf[ks][nt], S[nt], 0, 0, 0);

    float mrow[4];
    #pragma unroll
    for (int reg = 0; reg < 4; ++reg) mrow[reg] = -3.0e38f;
    #pragma unroll
    for (int nt = 0; nt < 4; ++nt) {
        const int col = k0 + nt * 16 + l16;
        #pragma unroll
        for (int reg = 0; reg < 4; ++reg) {
            const int row = row_base + quad * 4 + reg;
            const float s = (col > row) ? S[nt][reg] * 0.125f : -1e9f;
            S[nt][reg] = s;
            mrow[reg] = fmaxf(mrow[reg], s);
        }
    }
    #pragma unroll
    for (int off = 1; off < 16; off <<= 1)
        #pragma unroll
        for (int reg = 0; reg < 4; ++reg)
            mrow[reg] = fmaxf(mrow[reg], __shfl_xor(mrow[reg], off, 64));

    float alpha[4], ls[4];
    #pragma unroll
    for (int reg = 0; reg < 4; ++reg) {
        const float mn = fmaxf(m[reg], mrow[reg]);
        alpha[reg] = __expf(m[reg] - mn);
        m[reg] = mn;
        ls[reg] = 0.f;
    }
    #pragma unroll
    for (int nt = 0; nt < 4; ++nt)
        #pragma unroll
        for (int reg = 0; reg < 4; ++reg) {
            const float p = __expf(S[nt][reg] - m[reg]);
            S[nt][reg] = p;
            ls[reg] += p;
        }
    #pragma unroll
    for (int off = 1; off < 16; off <<= 1)
        #pragma unroll
        for (int reg = 0; reg < 4; ++reg)
            ls[reg] += __shfl_xor(ls[reg], off, 64);
    #pragma unroll
    for (int reg = 0; reg < 4; ++reg) l[reg] = l[reg] * alpha[reg] + ls[reg];

    // O rescale + publish P (C-layout -> A-layout via wave-local LDS)
    #pragma unroll
    for (int nt = 0; nt < 4; ++nt)
        #pragma unroll
        for (int reg = 0; reg < 4; ++reg) {
            O[nt][reg] *= alpha[reg];
            Psw[quad * 4 + reg][nt * 16 + l16] = f2bs(S[nt][reg]);
        }
    #pragma unroll
    for (int ks = 0; ks < 2; ++ks) {
        const bf16x8 pf = *(const bf16x8*)&Psw[l16][ks * 32 + quad * 8];
        #pragma unroll
        for (int nt = 0; nt < 4; ++nt) {
            const bf16x8 vf = *(const bf16x8*)&VsT[nt * 16 + l16][ks * 32 + quad * 8];
            O[nt] = __builtin_amdgcn_mfma_f32_16x16x32_bf16(pf, vf, O[nt], 0, 0, 0);
        }
    }
}

// ---------------------------------------------------------------------------
// Pair-folded MFMA flash attention, strict-upper mask (attend j > i).
// Block = 4 waves, handles q-tiles {p, 31-p} of one (b,h): ~33 tile-units
// each. K,V staged cooperatively in LDS (shared by waves), next tile
// register-prefetched. Pair p=0's B-tile sweeps all tiles so row S-1 gets
// the reference's uniform softmax (masked = exactly -1e9f -> p=1 chains).
// ---------------------------------------------------------------------------
__global__ __launch_bounds__(256, 2) void attn_mfma(
    const short* __restrict__ Qg, const short* __restrict__ Kg,
    const short* __restrict__ Vg, short* __restrict__ CTX)
{
    __shared__ __align__(16) short Ks [64][72];      // [key][d]
    __shared__ __align__(16) short VsT[64][72];      // [d][key]
    __shared__ __align__(16) short Ps[4][16][72];    // per-wave [m][key]

    const int tid  = threadIdx.x;
    const int lane = tid & 63, w = tid >> 6;
    const int quad = lane >> 4, l16 = lane & 15;
    const int p  = blockIdx.x;                // pair 0..15
    const int h  = blockIdx.y;
    const int b  = blockIdx.z;
    const size_t rb = (size_t)b * Sc;
    const int cb = h * DHc;

    const int qa0 = p * 64;
    const int qb0 = (NT - 1 - p) * 64;
    const int tA0 = p;
    const int tB0 = (p == 0) ? 0 : (NT - 1 - p);

    // Q fragments for both q-tiles
    bf16x8 qfA[2], qfB[2];
    {
        const short* qa = Qg + (rb + qa0 + w * 16 + l16) * (size_t)Dc + cb + quad * 8;
        qfA[0] = *(const bf16x8*)(qa);
        qfA[1] = *(const bf16x8*)(qa + 32);
        const short* qb = Qg + (rb + qb0 + w * 16 + l16) * (size_t)Dc + cb + quad * 8;
        qfB[0] = *(const bf16x8*)(qb);
        qfB[1] = *(const bf16x8*)(qb + 32);
    }

    float mA[4], lA[4], mB[4], lB[4];
    f32x4 OA[4] = {}, OB[4] = {};
    #pragma unroll
    for (int i = 0; i < 4; ++i) { mA[i] = -3.0e38f; lA[i] = 0.f; mB[i] = -3.0e38f; lB[i] = 0.f; }

    // staging assignment: thread stages 16 d of one key row (32 B K + 32 B V)
    const int skey = tid & 63, sseg = (tid >> 6) * 16;

    // stage first tile
    {
        const size_t g = (rb + tA0 * 64 + skey) * (size_t)Dc + cb + sseg;
        const bf16x8 k0v = *(const bf16x8*)(Kg + g);
        const bf16x8 k1v = *(const bf16x8*)(Kg + g + 8);
        const bf16x8 v0v = *(const bf16x8*)(Vg + g);
        const bf16x8 v1v = *(const bf16x8*)(Vg + g + 8);
        *(bf16x8*)&Ks[skey][sseg]     = k0v;
        *(bf16x8*)&Ks[skey][sseg + 8] = k1v;
        #pragma unroll
        for (int e = 0; e < 8; ++e) {
            VsT[sseg + e][skey]     = v0v[e];
            VsT[sseg + 8 + e][skey] = v1v[e];
        }
    }
    __syncthreads();

    for (int t = tA0; t < NT; ++t) {
        const bool havenext = (t + 1 < NT);
        bf16x8 pk0, pk1, pv0, pv1;
        if (havenext) {   // prefetch next tile into registers (drains at barrier)
            const size_t g = (rb + (t + 1) * 64 + skey) * (size_t)Dc + cb + sseg;
            pk0 = *(const bf16x8*)(Kg + g);
            pk1 = *(const bf16x8*)(Kg + g + 8);
            pv0 = *(const bf16x8*)(Vg + g);
            pv1 = *(const bf16x8*)(Vg + g + 8);
        }

        const int k0 = t * 64;
        // K fragments from LDS, shared by both q-tiles
        bf16x8 kf[2][4];
        #pragma unroll
        for (int ks = 0; ks < 2; ++ks)
            #pragma unroll
            for (int nt = 0; nt < 4; ++nt)
                kf[ks][nt] = *(const bf16x8*)&Ks[nt * 16 + l16][ks * 32 + quad * 8];

        qtile_step(qfA, kf, VsT, Ps[w], k0, qa0 + w * 16, quad, l16, mA, lA, OA);
        if (t >= tB0)
            qtile_step(qfB, kf, VsT, Ps[w], k0, qb0 + w * 16, quad, l16, mB, lB, OB);

        if (havenext) {
            __syncthreads();   // all waves done reading Ks/VsT
            *(bf16x8*)&Ks[skey][sseg]     = pk0;
            *(bf16x8*)&Ks[skey][sseg + 8] = pk1;
            #pragma unroll
            for (int e = 0; e < 8; ++e) {
                VsT[sseg + e][skey]     = pv0[e];
                VsT[sseg + 8 + e][skey] = pv1[e];
            }
            __syncthreads();
        }
    }

    #pragma unroll
    for (int reg = 0; reg < 4; ++reg) { lA[reg] = 1.0f / lA[reg]; lB[reg] = 1.0f / lB[reg]; }
    #pragma unroll
    for (int nt = 0; nt < 4; ++nt)
        #pragma unroll
        for (int reg = 0; reg < 4; ++reg) {
            const size_t ra = rb + qa0 + w * 16 + quad * 4 + reg;
            CTX[ra * Dc + cb + nt * 16 + l16] = f2bs(OA[nt][reg] * lA[reg]);
            const size_t rbq = rb + qb0 + w * 16 + quad * 4 + reg;
            CTX[rbq * Dc + cb + nt * 16 + l16] = f2bs(OB[nt][reg] * lB[reg]);
        }
}

// ---------------------------------------------------------------------------
// out = LayerNorm(x + attn_out) * gamma + beta; x f32, AO bf16, out f32
// ---------------------------------------------------------------------------
__global__ __launch_bounds__(256, 4) void resid_ln(
    const float* __restrict__ X, const short* __restrict__ AO,
    const float* __restrict__ gamma, const float* __restrict__ beta,
    float* __restrict__ out)
{
    const int r = blockIdx.x;
    const int t = threadIdx.x;
    const size_t base = (size_t)r * Dc + t * 4;

    const float4 x4 = *(const float4*)(X + base);
    const ushort4 a4 = *(const ushort4*)(AO + base);
    float y[4];
    y[0] = x4.x + bs2f(a4.x);
    y[1] = x4.y + bs2f(a4.y);
    y[2] = x4.z + bs2f(a4.z);
    y[3] = x4.w + bs2f(a4.w);

    float s  = y[0] + y[1] + y[2] + y[3];
    float s2 = y[0]*y[0] + y[1]*y[1] + y[2]*y[2] + y[3]*y[3];
    #pragma unroll
    for (int off = 1; off < 64; off <<= 1) {
        s  += __shfl_xor(s,  off, 64);
        s2 += __shfl_xor(s2, off, 64);
    }
    __shared__ float red[8];
    const int w = t >> 6;
    if ((t & 63) == 0) { red[w] = s; red[4 + w] = s2; }
    __syncthreads();
    s  = red[0] + red[1] + red[2] + red[3];
    s2 = red[4] + red[5] + red[6] + red[7];

    const float mu   = s * (1.0f / Dc);
    const float rstd = rsqrtf(s2 * (1.0f / Dc) - mu * mu + 1e-6f);

    const float4 g4 = *(const float4*)(gamma + t * 4);
    const float4 b4 = *(const float4*)(beta  + t * 4);
    float4 o;
    o.x = (y[0] - mu) * rstd * g4.x + b4.x;
    o.y = (y[1] - mu) * rstd * g4.y + b4.y;
    o.z = (y[2] - mu) * rstd * g4.z + b4.z;
    o.w = (y[3] - mu) * rstd * g4.w + b4.w;
    *(float4*)(out + base) = o;
}

// ---------------------------------------------------------------------------
extern "C" void kernel_launch(void* const* d_in, const int* in_sizes, int n_in,
                              void* d_out, int out_size, void* d_ws, size_t ws_size,
                              hipStream_t stream)
{
    (void)in_sizes; (void)n_in; (void)out_size; (void)ws_size;
    const float* x     = (const float*)d_in[0];
    const float* Wq    = (const float*)d_in[1];
    const float* bq    = (const float*)d_in[2];
    const float* Wk    = (const float*)d_in[3];
    const float* bk    = (const float*)d_in[4];
    const float* Wv    = (const float*)d_in[5];
    const float* bv    = (const float*)d_in[6];
    const float* Wo    = (const float*)d_in[7];
    const float* bo    = (const float*)d_in[8];
    const float* gamma = (const float*)d_in[9];
    const float* beta  = (const float*)d_in[10];
    float* out = (float*)d_out;

    const size_t matN = (size_t)BS * Dc;       // 4,194,304
    const size_t wN   = (size_t)Dc * Dc;       // 1,048,576
    short* xb = (short*)d_ws;
    short* WT = xb + matN;                     // 4 transposed weights
    short* Qb = WT + 4 * wN;
    short* Kb = Qb + matN;
    short* Vb = Kb + matN;
    short* Cx = Vb + matN;
    short* AO = Qb;                            // reuse after attention

    cast_x<<<matN / 1024, 256, 0, stream>>>(x, xb);

    dim3 gt(16, 16, 4);
    transpose_cast<<<gt, 256, 0, stream>>>(Wq, Wk, Wv, Wo, WT);

    dim3 gq(Dc / 128, BS / 128, 3);            // (8, 32, 3)
    gemm_bt<<<gq, 256, 0, stream>>>(xb, WT, bq, bk, bv, Qb);

    dim3 ga(16, Hc, Bc);                       // (16, 16, 2) paired q-tiles
    attn_mfma<<<ga, 256, 0, stream>>>(Qb, Kb, Vb, Cx);

    dim3 go(Dc / 128, BS / 128, 1);
    gemm_bt<<<go, 256, 0, stream>>>(Cx, WT + 3 * wN, bo, bo, bo, AO);

    resid_ln<<<BS, 256, 0, stream>>>(x, AO, gamma, beta, out);
}

// Round 5
// 263.427 us; speedup vs baseline: 4.5532x; 1.1794x over previous
//
#include <hip/hip_runtime.h>
#include <hip/hip_bf16.h>

typedef __hip_bfloat16 bf16;
typedef __attribute__((ext_vector_type(8))) short bf16x8;   // 8 bf16 = 4 VGPRs
typedef __attribute__((ext_vector_type(4))) float f32x4;

constexpr int Bc  = 2;
constexpr int Sc  = 2048;
constexpr int Dc  = 1024;
constexpr int Hc  = 16;
constexpr int DHc = 64;
constexpr int BS  = Bc * Sc;   // 4096 rows
constexpr int NT  = Sc / 64;   // 32 key tiles

__device__ __forceinline__ float bs2f(unsigned short u) {
    union { unsigned int i; float f; } v; v.i = ((unsigned int)u) << 16; return v.f;
}
__device__ __forceinline__ short f2bs(float x) {
    bf16 h = __float2bfloat16(x);
    return *reinterpret_cast<short*>(&h);
}

// ---------------------------------------------------------------------------
// cast x (f32) -> bf16, same layout
// ---------------------------------------------------------------------------
__global__ __launch_bounds__(256) void cast_x(const float* __restrict__ in,
                                              short* __restrict__ out) {
    const int i = (blockIdx.x * 256 + threadIdx.x) * 4;
    const float4 v = *(const float4*)(in + i);
    ushort4 o;
    o.x = (unsigned short)f2bs(v.x);
    o.y = (unsigned short)f2bs(v.y);
    o.z = (unsigned short)f2bs(v.z);
    o.w = (unsigned short)f2bs(v.w);
    *(ushort4*)(out + i) = o;
}

// ---------------------------------------------------------------------------
// transpose + cast: in f32 [1024 k][1024 n] -> out bf16 [n][k].  z picks W.
// ---------------------------------------------------------------------------
__global__ __launch_bounds__(256) void transpose_cast(
    const float* __restrict__ w0, const float* __restrict__ w1,
    const float* __restrict__ w2, const float* __restrict__ w3,
    short* __restrict__ outbase)
{
    __shared__ float T[64][65];
    const int z = blockIdx.z;
    const float* in = (z == 0) ? w0 : (z == 1) ? w1 : (z == 2) ? w2 : w3;
    short* out = outbase + (size_t)z * 1024 * 1024;
    const int k0 = blockIdx.x * 64, n0 = blockIdx.y * 64;
    const int t = threadIdx.x;
    #pragma unroll
    for (int it = 0; it < 4; ++it) {
        const int s = it * 256 + t;
        const int r = s >> 4, c = (s & 15) * 4;
        *(float4*)&T[r][c] = *(const float4*)(in + (size_t)(k0 + r) * 1024 + n0 + c);
    }
    __syncthreads();
    #pragma unroll
    for (int it = 0; it < 4; ++it) {
        const int s = it * 256 + t;
        const int rr = s >> 4, cc = (s & 15) * 4;   // rr: n-local, cc: k-local
        ushort4 o;
        o.x = (unsigned short)f2bs(T[cc + 0][rr]);
        o.y = (unsigned short)f2bs(T[cc + 1][rr]);
        o.z = (unsigned short)f2bs(T[cc + 2][rr]);
        o.w = (unsigned short)f2bs(T[cc + 3][rr]);
        *(ushort4*)(out + (size_t)(n0 + rr) * 1024 + k0 + cc) = o;
    }
}

// ---------------------------------------------------------------------------
// MFMA GEMM: C[z][4096][1024] = A[4096][1024] @ BT[z][n][k]^T + bias[z]
// bf16 in/out, f32 acc. 128x128 tile, BK=64, 256 thr = 4 waves of 64x64.
// ---------------------------------------------------------------------------
__global__ __launch_bounds__(256, 2) void gemm_bt(
    const short* __restrict__ A, const short* __restrict__ BTbase,
    const float* __restrict__ b0, const float* __restrict__ b1,
    const float* __restrict__ b2, short* __restrict__ Cbase)
{
    __shared__ __align__(16) short As[128][72];
    __shared__ __align__(16) short Bs[128][72];

    const int z = blockIdx.z;
    const short* BT = BTbase + (size_t)z * 1024 * 1024;
    const float* bias = (z == 0) ? b0 : (z == 1) ? b1 : b2;
    short* C = Cbase + (size_t)z * BS * Dc;

    const int t = threadIdx.x;
    const int lane = t & 63, w = t >> 6;
    const int quad = lane >> 4, l16 = lane & 15;
    const int wm = (w & 1) * 64, wn = (w >> 1) * 64;
    const int row0 = blockIdx.y * 128;
    const int col0 = blockIdx.x * 128;

    const int sr = t >> 1, sg = t & 1;   // staging: row, 32-elem segment

    f32x4 acc[4][4] = {};

    for (int kt = 0; kt < 1024; kt += 64) {
        __syncthreads();
        {
            const short* ap = A  + (size_t)(row0 + sr) * 1024 + kt + sg * 32;
            const short* bp = BT + (size_t)(col0 + sr) * 1024 + kt + sg * 32;
            #pragma unroll
            for (int i = 0; i < 4; ++i) {
                *(bf16x8*)&As[sr][sg * 32 + i * 8] = *(const bf16x8*)(ap + i * 8);
                *(bf16x8*)&Bs[sr][sg * 32 + i * 8] = *(const bf16x8*)(bp + i * 8);
            }
        }
        __syncthreads();
        #pragma unroll
        for (int ks = 0; ks < 2; ++ks) {
            bf16x8 av[4], bv[4];
            #pragma unroll
            for (int mt = 0; mt < 4; ++mt)
                av[mt] = *(const bf16x8*)&As[wm + mt * 16 + l16][ks * 32 + quad * 8];
            #pragma unroll
            for (int nt = 0; nt < 4; ++nt)
                bv[nt] = *(const bf16x8*)&Bs[wn + nt * 16 + l16][ks * 32 + quad * 8];
            #pragma unroll
            for (int mt = 0; mt < 4; ++mt)
                #pragma unroll
                for (int nt = 0; nt < 4; ++nt)
                    acc[mt][nt] = __builtin_amdgcn_mfma_f32_16x16x32_bf16(
                        av[mt], bv[nt], acc[mt][nt], 0, 0, 0);
        }
    }

    float bvv[4];
    #pragma unroll
    for (int nt = 0; nt < 4; ++nt) bvv[nt] = bias[col0 + wn + nt * 16 + l16];
    #pragma unroll
    for (int mt = 0; mt < 4; ++mt)
        #pragma unroll
        for (int reg = 0; reg < 4; ++reg) {
            const size_t row = row0 + wm + mt * 16 + quad * 4 + reg;
            #pragma unroll
            for (int nt = 0; nt < 4; ++nt) {
                const int col = col0 + wn + nt * 16 + l16;
                C[row * 1024 + col] = f2bs(acc[mt][nt][reg] + bvv[nt]);
            }
        }
}

// ---------------------------------------------------------------------------
// softmax(step) + PV for one 16-row q-fragment vs the staged 64-key tile.
// NO online max / rescale: p = exp(s) directly (scores are O(1); masked
// entries get s = -87 -> p ~ 1.6e-38, invisible next to any allowed key).
// Per-lane l accumulates across tiles; ONE butterfly at the end.
// Layouts (HW-validated R3/R4): A-frag A[m=l16][k=quad*8+j]; B-frag
// B[k=quad*8+j][n=l16]; C/D row=quad*4+reg, col=l16.
// ---------------------------------------------------------------------------
__device__ __forceinline__ void qtile_step(
    const bf16x8 (&qf)[2], const bf16x8 (&kf)[2][4],
    const short (&VsT)[64][72], short (&Psw)[16][72],
    const int k0, const int row_base,           // row = row_base + quad*4 + reg
    const int quad, const int l16,
    float (&l)[4], f32x4 (&O)[4])
{
    f32x4 S[4] = {};
    #pragma unroll
    for (int ks = 0; ks < 2; ++ks)
        #pragma unroll
        for (int nt = 0; nt < 4; ++nt)
            S[nt] = __builtin_amdgcn_mfma_f32_16x16x32_bf16(qf[ks], kf[ks][nt], S[nt], 0, 0, 0);

    #pragma unroll
    for (int nt = 0; nt < 4; ++nt) {
        const int col = k0 + nt * 16 + l16;
        #pragma unroll
        for (int reg = 0; reg < 4; ++reg) {
            const int row = row_base + quad * 4 + reg;
            const float s = (col > row) ? fminf(S[nt][reg] * 0.125f, 80.f) : -87.0f;
            const float p = __expf(s);
            S[nt][reg] = p;
            l[reg] += p;
        }
    }

    // publish P (C-layout -> A-layout via wave-local LDS)
    #pragma unroll
    for (int nt = 0; nt < 4; ++nt)
        #pragma unroll
        for (int reg = 0; reg < 4; ++reg)
            Psw[quad * 4 + reg][nt * 16 + l16] = f2bs(S[nt][reg]);

    #pragma unroll
    for (int ks = 0; ks < 2; ++ks) {
        const bf16x8 pf = *(const bf16x8*)&Psw[l16][ks * 32 + quad * 8];
        #pragma unroll
        for (int nt = 0; nt < 4; ++nt) {
            const bf16x8 vf = *(const bf16x8*)&VsT[nt * 16 + l16][ks * 32 + quad * 8];
            O[nt] = __builtin_amdgcn_mfma_f32_16x16x32_bf16(pf, vf, O[nt], 0, 0, 0);
        }
    }
}

// ---------------------------------------------------------------------------
// Pair-folded MFMA flash attention, strict-upper mask (attend j > i).
// Block = 4 waves, q-tiles {p, 31-p} of one (b,h): A sweeps tiles [p,32),
// B sweeps [31-p, 32) -> exactly 33 tile-units per block, all p.
// Row S-1 (fully masked -> reference gives uniform softmax) is fixed up by
// the vmean kernel afterwards.
// ---------------------------------------------------------------------------
__global__ __launch_bounds__(256, 2) void attn_mfma(
    const short* __restrict__ Qg, const short* __restrict__ Kg,
    const short* __restrict__ Vg, short* __restrict__ CTX)
{
    __shared__ __align__(16) short Ks [64][72];      // [key][d]
    __shared__ __align__(16) short VsT[64][72];      // [d][key]
    __shared__ __align__(16) short Ps[4][16][72];    // per-wave [m][key]

    const int tid  = threadIdx.x;
    const int lane = tid & 63, w = tid >> 6;
    const int quad = lane >> 4, l16 = lane & 15;
    const int p  = blockIdx.x;                // pair 0..15
    const int h  = blockIdx.y;
    const int b  = blockIdx.z;
    const size_t rb = (size_t)b * Sc;
    const int cb = h * DHc;

    const int qa0 = p * 64;
    const int qb0 = (NT - 1 - p) * 64;
    const int tA0 = p;
    const int tB0 = NT - 1 - p;

    // Q fragments for both q-tiles
    bf16x8 qfA[2], qfB[2];
    {
        const short* qa = Qg + (rb + qa0 + w * 16 + l16) * (size_t)Dc + cb + quad * 8;
        qfA[0] = *(const bf16x8*)(qa);
        qfA[1] = *(const bf16x8*)(qa + 32);
        const short* qb = Qg + (rb + qb0 + w * 16 + l16) * (size_t)Dc + cb + quad * 8;
        qfB[0] = *(const bf16x8*)(qb);
        qfB[1] = *(const bf16x8*)(qb + 32);
    }

    float lA[4] = {}, lB[4] = {};
    f32x4 OA[4] = {}, OB[4] = {};

    // staging assignment: thread stages 16 d of one key row (32 B K + 32 B V)
    const int skey = tid & 63, sseg = (tid >> 6) * 16;

    // stage first tile
    {
        const size_t g = (rb + tA0 * 64 + skey) * (size_t)Dc + cb + sseg;
        const bf16x8 k0v = *(const bf16x8*)(Kg + g);
        const bf16x8 k1v = *(const bf16x8*)(Kg + g + 8);
        const bf16x8 v0v = *(const bf16x8*)(Vg + g);
        const bf16x8 v1v = *(const bf16x8*)(Vg + g + 8);
        *(bf16x8*)&Ks[skey][sseg]     = k0v;
        *(bf16x8*)&Ks[skey][sseg + 8] = k1v;
        #pragma unroll
        for (int e = 0; e < 8; ++e) {
            VsT[sseg + e][skey]     = v0v[e];
            VsT[sseg + 8 + e][skey] = v1v[e];
        }
    }
    __syncthreads();

    for (int t = tA0; t < NT; ++t) {
        const bool havenext = (t + 1 < NT);
        bf16x8 pk0, pk1, pv0, pv1;
        if (havenext) {   // prefetch next tile into registers (drains at barrier)
            const size_t g = (rb + (t + 1) * 64 + skey) * (size_t)Dc + cb + sseg;
            pk0 = *(const bf16x8*)(Kg + g);
            pk1 = *(const bf16x8*)(Kg + g + 8);
            pv0 = *(const bf16x8*)(Vg + g);
            pv1 = *(const bf16x8*)(Vg + g + 8);
        }

        const int k0 = t * 64;
        // K fragments from LDS, shared by both q-tiles
        bf16x8 kf[2][4];
        #pragma unroll
        for (int ks = 0; ks < 2; ++ks)
            #pragma unroll
            for (int nt = 0; nt < 4; ++nt)
                kf[ks][nt] = *(const bf16x8*)&Ks[nt * 16 + l16][ks * 32 + quad * 8];

        qtile_step(qfA, kf, VsT, Ps[w], k0, qa0 + w * 16, quad, l16, lA, OA);
        if (t >= tB0)
            qtile_step(qfB, kf, VsT, Ps[w], k0, qb0 + w * 16, quad, l16, lB, OB);

        if (havenext) {
            __syncthreads();   // all waves done reading Ks/VsT
            *(bf16x8*)&Ks[skey][sseg]     = pk0;
            *(bf16x8*)&Ks[skey][sseg + 8] = pk1;
            #pragma unroll
            for (int e = 0; e < 8; ++e) {
                VsT[sseg + e][skey]     = pv0[e];
                VsT[sseg + 8 + e][skey] = pv1[e];
            }
            __syncthreads();
        }
    }

    // single deferred 16-lane reduction of l, then normalize + store
    #pragma unroll
    for (int off = 1; off < 16; off <<= 1)
        #pragma unroll
        for (int reg = 0; reg < 4; ++reg) {
            lA[reg] += __shfl_xor(lA[reg], off, 64);
            lB[reg] += __shfl_xor(lB[reg], off, 64);
        }
    #pragma unroll
    for (int reg = 0; reg < 4; ++reg) { lA[reg] = 1.0f / lA[reg]; lB[reg] = 1.0f / lB[reg]; }
    #pragma unroll
    for (int nt = 0; nt < 4; ++nt)
        #pragma unroll
        for (int reg = 0; reg < 4; ++reg) {
            const size_t ra = rb + qa0 + w * 16 + quad * 4 + reg;
            CTX[ra * Dc + cb + nt * 16 + l16] = f2bs(OA[nt][reg] * lA[reg]);
            const size_t rbq = rb + qb0 + w * 16 + quad * 4 + reg;
            CTX[rbq * Dc + cb + nt * 16 + l16] = f2bs(OB[nt][reg] * lB[reg]);
        }
}

// ---------------------------------------------------------------------------
// Row S-1 is fully masked: reference softmax of all-(-1e9) is exactly
// uniform 1/S -> ctx = mean_j V[b,j,h,:]. Overwrites attn's placeholder.
// ---------------------------------------------------------------------------
__global__ __launch_bounds__(256) void vmean(const short* __restrict__ V,
                                             short* __restrict__ CTX)
{
    const int h = blockIdx.x, b = blockIdx.y;
    const int t = threadIdx.x;
    const int dh = t & 63, ck = t >> 6;      // 4 chunks of 512 keys
    float s = 0.f;
    const short* vp = V + ((size_t)b * Sc + ck * 512) * Dc + h * DHc + dh;
    for (int j = 0; j < 512; ++j) s += bs2f(vp[(size_t)j * Dc]);
    __shared__ float red[4][64];
    red[ck][dh] = s;
    __syncthreads();
    if (ck == 0) {
        const float tot = (red[0][dh] + red[1][dh] + red[2][dh] + red[3][dh]) * (1.f / Sc);
        CTX[((size_t)b * Sc + Sc - 1) * Dc + h * DHc + dh] = f2bs(tot);
    }
}

// ---------------------------------------------------------------------------
// out = LayerNorm(x + attn_out) * gamma + beta; x f32, AO bf16, out f32
// ---------------------------------------------------------------------------
__global__ __launch_bounds__(256, 4) void resid_ln(
    const float* __restrict__ X, const short* __restrict__ AO,
    const float* __restrict__ gamma, const float* __restrict__ beta,
    float* __restrict__ out)
{
    const int r = blockIdx.x;
    const int t = threadIdx.x;
    const size_t base = (size_t)r * Dc + t * 4;

    const float4 x4 = *(const float4*)(X + base);
    const ushort4 a4 = *(const ushort4*)(AO + base);
    float y[4];
    y[0] = x4.x + bs2f(a4.x);
    y[1] = x4.y + bs2f(a4.y);
    y[2] = x4.z + bs2f(a4.z);
    y[3] = x4.w + bs2f(a4.w);

    float s  = y[0] + y[1] + y[2] + y[3];
    float s2 = y[0]*y[0] + y[1]*y[1] + y[2]*y[2] + y[3]*y[3];
    #pragma unroll
    for (int off = 1; off < 64; off <<= 1) {
        s  += __shfl_xor(s,  off, 64);
        s2 += __shfl_xor(s2, off, 64);
    }
    __shared__ float red[8];
    const int w = t >> 6;
    if ((t & 63) == 0) { red[w] = s; red[4 + w] = s2; }
    __syncthreads();
    s  = red[0] + red[1] + red[2] + red[3];
    s2 = red[4] + red[5] + red[6] + red[7];

    const float mu   = s * (1.0f / Dc);
    const float rstd = rsqrtf(s2 * (1.0f / Dc) - mu * mu + 1e-6f);

    const float4 g4 = *(const float4*)(gamma + t * 4);
    const float4 b4 = *(const float4*)(beta  + t * 4);
    float4 o;
    o.x = (y[0] - mu) * rstd * g4.x + b4.x;
    o.y = (y[1] - mu) * rstd * g4.y + b4.y;
    o.z = (y[2] - mu) * rstd * g4.z + b4.z;
    o.w = (y[3] - mu) * rstd * g4.w + b4.w;
    *(float4*)(out + base) = o;
}

// ---------------------------------------------------------------------------
extern "C" void kernel_launch(void* const* d_in, const int* in_sizes, int n_in,
                              void* d_out, int out_size, void* d_ws, size_t ws_size,
                              hipStream_t stream)
{
    (void)in_sizes; (void)n_in; (void)out_size; (void)ws_size;
    const float* x     = (const float*)d_in[0];
    const float* Wq    = (const float*)d_in[1];
    const float* bq    = (const float*)d_in[2];
    const float* Wk    = (const float*)d_in[3];
    const float* bk    = (const float*)d_in[4];
    const float* Wv    = (const float*)d_in[5];
    const float* bv    = (const float*)d_in[6];
    const float* Wo    = (const float*)d_in[7];
    const float* bo    = (const float*)d_in[8];
    const float* gamma = (const float*)d_in[9];
    const float* beta  = (const float*)d_in[10];
    float* out = (float*)d_out;

    const size_t matN = (size_t)BS * Dc;       // 4,194,304
    const size_t wN   = (size_t)Dc * Dc;       // 1,048,576
    short* xb = (short*)d_ws;
    short* WT = xb + matN;                     // 4 transposed weights
    short* Qb = WT + 4 * wN;
    short* Kb = Qb + matN;
    short* Vb = Kb + matN;
    short* Cx = Vb + matN;
    short* AO = Qb;                            // reuse after attention

    cast_x<<<matN / 1024, 256, 0, stream>>>(x, xb);

    dim3 gt(16, 16, 4);
    transpose_cast<<<gt, 256, 0, stream>>>(Wq, Wk, Wv, Wo, WT);

    dim3 gq(Dc / 128, BS / 128, 3);            // (8, 32, 3)
    gemm_bt<<<gq, 256, 0, stream>>>(xb, WT, bq, bk, bv, Qb);

    dim3 ga(16, Hc, Bc);                       // (16, 16, 2) paired q-tiles
    attn_mfma<<<ga, 256, 0, stream>>>(Qb, Kb, Vb, Cx);

    dim3 gv(Hc, Bc);
    vmean<<<gv, 256, 0, stream>>>(Vb, Cx);     // fix up row S-1 (uniform softmax)

    dim3 go(Dc / 128, BS / 128, 1);
    gemm_bt<<<go, 256, 0, stream>>>(Cx, WT + 3 * wN, bo, bo, bo, AO);

    resid_ln<<<BS, 256, 0, stream>>>(x, AO, gamma, beta, out);
}